// Round 1
// baseline (203.819 us; speedup 1.0000x reference)
//
#include <hip/hip_runtime.h>
#include <math.h>

#define N 8192
#define D 64
#define CHUNKS 128
#define CROWS 64  // N / CHUNKS

// K1: h = x @ Wt  [N,64]x[64,64]; f1 = h@a1+b1; f2 = h@a2+b2
__global__ __launch_bounds__(256) void k1_gemm(
    const float* __restrict__ x, const float* __restrict__ Wt,
    const float* __restrict__ a1, const float* __restrict__ b1,
    const float* __restrict__ a2, const float* __restrict__ b2,
    float* __restrict__ h, float* __restrict__ f1, float* __restrict__ f2) {
  __shared__ float WtS[D * D];
  __shared__ float xs[16 * D];
  int t = threadIdx.x;
  int rowBase = blockIdx.x * 16;
  for (int i = t; i < D * D; i += 256) WtS[i] = Wt[i];
  for (int i = t; i < 16 * D; i += 256) xs[i] = x[rowBase * D + i];
  __syncthreads();
  int d = t & 63;
  int w = t >> 6;  // wave id 0..3
  float a1d = a1[d], a2d = a2[d];
  float b1v = b1[0], b2v = b2[0];
  for (int it = 0; it < 4; ++it) {
    int rl = w + it * 4;  // 0..15
    float acc = 0.f;
#pragma unroll
    for (int k = 0; k < D; ++k) acc += xs[rl * D + k] * WtS[k * D + d];
    int grow = rowBase + rl;
    h[grow * D + d] = acc;
    float v1 = acc * a1d;
    float v2 = acc * a2d;
#pragma unroll
    for (int off = 32; off > 0; off >>= 1) {
      v1 += __shfl_xor(v1, off);
      v2 += __shfl_xor(v2, off);
    }
    if (d == 0) {
      f1[grow] = v1 + b1v;
      f2[grow] = v2 + b2v;
    }
  }
}

// K2: bitonic sort f2 ascending (keys + permutation) in LDS, single block.
// Also emits the per-element weights in sorted order:
//   wsm[r] = exp(0.2*f2s[r])  (negative-branch), wbg[r] = exp(f2s[r]) (positive-branch)
__global__ __launch_bounds__(1024) void k2_sort(
    const float* __restrict__ f2, float* __restrict__ f2s,
    int* __restrict__ perm, float* __restrict__ wsm, float* __restrict__ wbg) {
  __shared__ float key[N];
  __shared__ int idx[N];
  int t = threadIdx.x;
  for (int i = t; i < N; i += 1024) {
    key[i] = f2[i];
    idx[i] = i;
  }
  for (int size = 2; size <= N; size <<= 1) {
    for (int stride = size >> 1; stride > 0; stride >>= 1) {
      __syncthreads();
      for (int pp = t; pp < N / 2; pp += 1024) {
        int i = ((pp & ~(stride - 1)) << 1) | (pp & (stride - 1));
        int j = i | stride;
        bool up = ((i & size) == 0);
        float ki = key[i], kj = key[j];
        bool sw = up ? (ki > kj) : (ki < kj);
        if (sw) {
          key[i] = kj;
          key[j] = ki;
          int ti = idx[i];
          idx[i] = idx[j];
          idx[j] = ti;
        }
      }
    }
  }
  __syncthreads();
  for (int i = t; i < N; i += 1024) {
    float k = key[i];
    f2s[i] = k;
    perm[i] = idx[i];
    wsm[i] = expf(0.2f * k);
    wbg[i] = expf(k);
  }
}

// K3a: per-chunk partial sums of wsm*h_sorted and wbg*h_sorted (all 64 dims)
__global__ __launch_bounds__(256) void k3a_partials(
    const float* __restrict__ h, const int* __restrict__ perm,
    const float* __restrict__ wsm, const float* __restrict__ wbg,
    float* __restrict__ part_s, float* __restrict__ part_b) {
  int c = blockIdx.x;
  int t = threadIdx.x;
  int d = t & 63, r0 = t >> 6;
  float accS = 0.f, accB = 0.f;
  for (int r = r0; r < CROWS; r += 4) {
    int gr = c * CROWS + r;
    int j = perm[gr];
    float v = h[(size_t)j * D + d];
    accS += wsm[gr] * v;
    accB += wbg[gr] * v;
  }
  __shared__ float rS[256], rB[256];
  rS[t] = accS;
  rB[t] = accB;
  __syncthreads();
  if (r0 == 0) {
    part_s[c * D + d] = rS[d] + rS[64 + d] + rS[128 + d] + rS[192 + d];
    part_b[c * D + d] = rB[d] + rB[64 + d] + rB[128 + d] + rB[192 + d];
  }
}

// K3b: scan chunk partials into per-chunk offsets (prefix for small, suffix
// for big), plus full scalar prefix p[k] and suffix s[k] over the weights.
__global__ __launch_bounds__(256) void k3b_offsets(
    const float* __restrict__ part_s, const float* __restrict__ part_b,
    float* __restrict__ off_s, float* __restrict__ off_b,
    const float* __restrict__ wsm, const float* __restrict__ wbg,
    float* __restrict__ p, float* __restrict__ s) {
  int t = threadIdx.x;
  if (t < 64) {
    float run = 0.f;
    for (int c = 0; c < CHUNKS; ++c) {
      off_s[c * D + t] = run;
      run += part_s[c * D + t];
    }
  } else if (t < 128) {
    int d = t - 64;
    float run = 0.f;
    for (int c = CHUNKS - 1; c >= 0; --c) {
      off_b[c * D + d] = run;
      run += part_b[c * D + d];
    }
  }
  __shared__ float lsum[256];
  __shared__ float lofs[256];
  int base = t * 32;
  float loc = 0.f;
  for (int i = 0; i < 32; ++i) loc += wsm[base + i];
  lsum[t] = loc;
  __syncthreads();
  if (t == 0) {
    float run = 0.f;
    for (int i = 0; i < 256; ++i) {
      lofs[i] = run;
      run += lsum[i];
    }
  }
  __syncthreads();
  {
    float run = lofs[t];
    for (int i = 0; i < 32; ++i) {
      p[base + i] = run;
      run += wsm[base + i];
    }
    if (t == 255) p[N] = run;
  }
  __syncthreads();
  loc = 0.f;
  for (int i = 0; i < 32; ++i) loc += wbg[base + i];
  lsum[t] = loc;
  __syncthreads();
  if (t == 0) {
    float run = 0.f;
    for (int i = 255; i >= 0; --i) {
      lofs[i] = run;
      run += lsum[i];
    }
    s[N] = 0.f;
  }
  __syncthreads();
  {
    float run = lofs[t];
    for (int i = 31; i >= 0; --i) {
      run += wbg[base + i];
      s[base + i] = run;
    }
  }
}

// K3c: write full vector prefix P[k][d] (exclusive, small weights) and
// suffix S[k][d] (inclusive-from-k, big weights), k in [0..N].
__global__ __launch_bounds__(64) void k3c_scan(
    const float* __restrict__ h, const int* __restrict__ perm,
    const float* __restrict__ wsm, const float* __restrict__ wbg,
    const float* __restrict__ off_s, const float* __restrict__ off_b,
    float* __restrict__ Pm, float* __restrict__ Sm) {
  int c = blockIdx.x;
  int d = threadIdx.x;
  int base = c * CROWS;
  float runP = off_s[c * D + d];
  for (int r = 0; r < CROWS; ++r) {
    int gr = base + r;
    Pm[(size_t)gr * D + d] = runP;
    runP += wsm[gr] * h[(size_t)perm[gr] * D + d];
  }
  if (c == CHUNKS - 1) {
    Pm[(size_t)N * D + d] = runP;
    Sm[(size_t)N * D + d] = 0.f;
  }
  float runS = off_b[c * D + d];
  for (int r = CROWS - 1; r >= 0; --r) {
    int gr = base + r;
    runS += wbg[gr] * h[(size_t)perm[gr] * D + d];
    Sm[(size_t)gr * D + d] = runS;
  }
}

// K4: per (row, dim): binary-search split point, combine, ELU.
__global__ __launch_bounds__(256) void k4_out(
    const float* __restrict__ f1, const float* __restrict__ f2s,
    const float* __restrict__ p, const float* __restrict__ s,
    const float* __restrict__ Pm, const float* __restrict__ Sm,
    float* __restrict__ out) {
  int g = blockIdx.x * 256 + threadIdx.x;
  int row = g >> 6, d = g & 63;
  float f1v = f1[row];
  float thr = -f1v;
  int lo = 0, hi = N;
  while (lo < hi) {
    int mid = (lo + hi) >> 1;
    if (f2s[mid] < thr)
      lo = mid + 1;
    else
      hi = mid;
  }
  float e1 = expf(f1v), e2 = expf(0.2f * f1v);
  size_t k64 = (size_t)lo * D + d;
  float num = e1 * Sm[k64] + e2 * Pm[k64];
  float den = e1 * s[lo] + e2 * p[lo];
  float v = num / den;
  out[g] = v > 0.f ? v : expm1f(v);
}

extern "C" void kernel_launch(void* const* d_in, const int* in_sizes, int n_in,
                              void* d_out, int out_size, void* d_ws,
                              size_t ws_size, hipStream_t stream) {
  const float* x = (const float*)d_in[0];
  const float* Wt = (const float*)d_in[1];
  const float* a1 = (const float*)d_in[2];
  const float* b1 = (const float*)d_in[3];
  const float* a2 = (const float*)d_in[4];
  const float* b2 = (const float*)d_in[5];
  float* out = (float*)d_out;

  float* ws = (float*)d_ws;
  float* h = ws;        ws += N * D;
  float* f1 = ws;       ws += N;
  float* f2v = ws;      ws += N;
  float* f2s = ws;      ws += N;
  int* perm = (int*)ws; ws += N;
  float* wsm = ws;      ws += N;
  float* wbg = ws;      ws += N;
  float* part_s = ws;   ws += CHUNKS * D;
  float* part_b = ws;   ws += CHUNKS * D;
  float* off_s = ws;    ws += CHUNKS * D;
  float* off_b = ws;    ws += CHUNKS * D;
  float* pp = ws;       ws += (N + 1);
  float* ss = ws;       ws += (N + 1);
  float* Pm = ws;       ws += (size_t)(N + 1) * D;
  float* Sm = ws;       ws += (size_t)(N + 1) * D;

  k1_gemm<<<N / 16, 256, 0, stream>>>(x, Wt, a1, b1, a2, b2, h, f1, f2v);
  k2_sort<<<1, 1024, 0, stream>>>(f2v, f2s, perm, wsm, wbg);
  k3a_partials<<<CHUNKS, 256, 0, stream>>>(h, perm, wsm, wbg, part_s, part_b);
  k3b_offsets<<<1, 256, 0, stream>>>(part_s, part_b, off_s, off_b, wsm, wbg, pp, ss);
  k3c_scan<<<CHUNKS, 64, 0, stream>>>(h, perm, wsm, wbg, off_s, off_b, Pm, Sm);
  k4_out<<<(N * D) / 256, 256, 0, stream>>>(f1, f2s, pp, ss, Pm, Sm, out);
}

// Round 2
// 153.133 us; speedup vs baseline: 1.3310x; 1.3310x over previous
//
#include <hip/hip_runtime.h>
#include <math.h>

#define N 8192
#define D 64
#define CHUNKS 128
#define CROWS 64  // N / CHUNKS

typedef unsigned long long u64;

__device__ __forceinline__ unsigned ordered_bits(float v) {
  unsigned u = __float_as_uint(v);
  return u ^ (((int)u >> 31) | 0x80000000u);
}

// K1: h = x @ Wt  [N,64]x[64,64]; f1 = h@a1+b1; f2 = h@a2+b2.
// Also emits the strictly-distinct 64-bit sort keys for f2 and the per-row
// threshold keys for -f1 (used by the counting-rank kernel).
__global__ __launch_bounds__(256) void k1_gemm(
    const float* __restrict__ x, const float* __restrict__ Wt,
    const float* __restrict__ a1, const float* __restrict__ b1,
    const float* __restrict__ a2, const float* __restrict__ b2,
    float* __restrict__ h, float* __restrict__ f1, float* __restrict__ f2,
    u64* __restrict__ key64, u64* __restrict__ thrkey) {
  __shared__ float WtS[D * D];
  __shared__ float xs[16 * D];
  int t = threadIdx.x;
  int rowBase = blockIdx.x * 16;
  for (int i = t; i < D * D; i += 256) WtS[i] = Wt[i];
  for (int i = t; i < 16 * D; i += 256) xs[i] = x[rowBase * D + i];
  __syncthreads();
  int d = t & 63;
  int w = t >> 6;  // wave id 0..3
  float a1d = a1[d], a2d = a2[d];
  float b1v = b1[0], b2v = b2[0];
  for (int it = 0; it < 4; ++it) {
    int rl = w + it * 4;  // 0..15
    float acc = 0.f;
#pragma unroll
    for (int k = 0; k < D; ++k) acc += xs[rl * D + k] * WtS[k * D + d];
    int grow = rowBase + rl;
    h[grow * D + d] = acc;
    float v1 = acc * a1d;
    float v2 = acc * a2d;
#pragma unroll
    for (int off = 32; off > 0; off >>= 1) {
      v1 += __shfl_xor(v1, off);
      v2 += __shfl_xor(v2, off);
    }
    if (d == 0) {
      float F1 = v1 + b1v;
      float F2 = v2 + b2v;
      f1[grow] = F1;
      f2[grow] = F2;
      key64[grow] = ((u64)ordered_bits(F2) << 13) | (unsigned)grow;
      thrkey[grow] = ((u64)ordered_bits(-F1) << 13);
    }
  }
}

// K2: counting rank. 16384 queries (8192 element keys -> scatter permutation,
// 8192 threshold keys -> per-row split point). Each block handles 64 queries;
// 4 waves each scan a quarter of the key array (wave-uniform addresses ->
// scalar loads), partial counts combined in LDS.
__global__ __launch_bounds__(256) void k2_count(
    const u64* __restrict__ key64, const u64* __restrict__ thrkey,
    const float* __restrict__ f2,
    int* __restrict__ perm, float* __restrict__ wsm, float* __restrict__ wbg,
    int* __restrict__ ksplit) {
  int tid = threadIdx.x;
  int w = tid >> 6, lane = tid & 63;
  int q = blockIdx.x * 64 + lane;
  u64 qk = (q < N) ? key64[q] : thrkey[q - N];
  int base = w * (N / 4);
  int cnt = 0;
#pragma unroll 16
  for (int l = 0; l < N / 4; ++l) {
    cnt += (key64[base + l] < qk) ? 1 : 0;
  }
  __shared__ int part[4][64];
  part[w][lane] = cnt;
  __syncthreads();
  if (w == 0) {
    int total = part[0][lane] + part[1][lane] + part[2][lane] + part[3][lane];
    if (q < N) {
      float v = f2[q];
      perm[total] = q;
      wsm[total] = expf(0.2f * v);
      wbg[total] = expf(v);
    } else {
      ksplit[q - N] = total;
    }
  }
}

// K3a: per-chunk partial sums of wsm*h_sorted and wbg*h_sorted (all 64 dims)
__global__ __launch_bounds__(256) void k3a_partials(
    const float* __restrict__ h, const int* __restrict__ perm,
    const float* __restrict__ wsm, const float* __restrict__ wbg,
    float* __restrict__ part_s, float* __restrict__ part_b) {
  int c = blockIdx.x;
  int t = threadIdx.x;
  int d = t & 63, r0 = t >> 6;
  float accS = 0.f, accB = 0.f;
  for (int r = r0; r < CROWS; r += 4) {
    int gr = c * CROWS + r;
    int j = perm[gr];
    float v = h[(size_t)j * D + d];
    accS += wsm[gr] * v;
    accB += wbg[gr] * v;
  }
  __shared__ float rS[256], rB[256];
  rS[t] = accS;
  rB[t] = accB;
  __syncthreads();
  if (r0 == 0) {
    part_s[c * D + d] = rS[d] + rS[64 + d] + rS[128 + d] + rS[192 + d];
    part_b[c * D + d] = rB[d] + rB[64 + d] + rB[128 + d] + rB[192 + d];
  }
}

// K3b: scan chunk partials into per-chunk offsets (prefix for small, suffix
// for big), plus full scalar prefix p[k] and suffix s[k] over the weights.
__global__ __launch_bounds__(256) void k3b_offsets(
    const float* __restrict__ part_s, const float* __restrict__ part_b,
    float* __restrict__ off_s, float* __restrict__ off_b,
    const float* __restrict__ wsm, const float* __restrict__ wbg,
    float* __restrict__ p, float* __restrict__ s) {
  int t = threadIdx.x;
  if (t < 64) {
    float run = 0.f;
    for (int c = 0; c < CHUNKS; ++c) {
      off_s[c * D + t] = run;
      run += part_s[c * D + t];
    }
  } else if (t < 128) {
    int d = t - 64;
    float run = 0.f;
    for (int c = CHUNKS - 1; c >= 0; --c) {
      off_b[c * D + d] = run;
      run += part_b[c * D + d];
    }
  }
  __shared__ float lsum[256];
  __shared__ float lofs[256];
  int base = t * 32;
  float loc = 0.f;
  for (int i = 0; i < 32; ++i) loc += wsm[base + i];
  lsum[t] = loc;
  __syncthreads();
  if (t == 0) {
    float run = 0.f;
    for (int i = 0; i < 256; ++i) {
      lofs[i] = run;
      run += lsum[i];
    }
  }
  __syncthreads();
  {
    float run = lofs[t];
    for (int i = 0; i < 32; ++i) {
      p[base + i] = run;
      run += wsm[base + i];
    }
    if (t == 255) p[N] = run;
  }
  __syncthreads();
  loc = 0.f;
  for (int i = 0; i < 32; ++i) loc += wbg[base + i];
  lsum[t] = loc;
  __syncthreads();
  if (t == 0) {
    float run = 0.f;
    for (int i = 255; i >= 0; --i) {
      lofs[i] = run;
      run += lsum[i];
    }
    s[N] = 0.f;
  }
  __syncthreads();
  {
    float run = lofs[t];
    for (int i = 31; i >= 0; --i) {
      run += wbg[base + i];
      s[base + i] = run;
    }
  }
}

// K3c: full vector prefix P[k][d] (exclusive, small weights) and suffix
// S[k][d] (inclusive-from-k, big weights). Chunk staged in LDS first so the
// serial scans hit LDS, not dependent global gathers.
__global__ __launch_bounds__(64) void k3c_scan(
    const float* __restrict__ h, const int* __restrict__ perm,
    const float* __restrict__ wsm, const float* __restrict__ wbg,
    const float* __restrict__ off_s, const float* __restrict__ off_b,
    float* __restrict__ Pm, float* __restrict__ Sm) {
  __shared__ float hs[CROWS * D];
  __shared__ float wS[CROWS], wB[CROWS];
  int c = blockIdx.x;
  int d = threadIdx.x;
  int base = c * CROWS;
  int pj = perm[base + d];  // one perm entry per lane (CROWS == 64)
  wS[d] = wsm[base + d];
  wB[d] = wbg[base + d];
#pragma unroll 8
  for (int r = 0; r < CROWS; ++r) {
    int j = __shfl(pj, r);
    hs[r * D + d] = h[(size_t)j * D + d];  // 64 independent coalesced loads
  }
  __syncthreads();
  float runP = off_s[c * D + d];
#pragma unroll 4
  for (int r = 0; r < CROWS; ++r) {
    Pm[(size_t)(base + r) * D + d] = runP;
    runP += wS[r] * hs[r * D + d];
  }
  if (c == CHUNKS - 1) {
    Pm[(size_t)N * D + d] = runP;
    Sm[(size_t)N * D + d] = 0.f;
  }
  float runS = off_b[c * D + d];
#pragma unroll 4
  for (int r = CROWS - 1; r >= 0; --r) {
    runS += wB[r] * hs[r * D + d];
    Sm[(size_t)(base + r) * D + d] = runS;
  }
}

// K4: per (row, dim): combine at precomputed split point, ELU.
__global__ __launch_bounds__(256) void k4_out(
    const float* __restrict__ f1, const int* __restrict__ ksplit,
    const float* __restrict__ p, const float* __restrict__ s,
    const float* __restrict__ Pm, const float* __restrict__ Sm,
    float* __restrict__ out) {
  int g = blockIdx.x * 256 + threadIdx.x;
  int row = g >> 6, d = g & 63;
  float f1v = f1[row];
  int k = ksplit[row];
  float e1 = expf(f1v), e2 = expf(0.2f * f1v);
  size_t k64 = (size_t)k * D + d;
  float num = e1 * Sm[k64] + e2 * Pm[k64];
  float den = e1 * s[k] + e2 * p[k];
  float v = num / den;
  out[g] = v > 0.f ? v : expm1f(v);
}

extern "C" void kernel_launch(void* const* d_in, const int* in_sizes, int n_in,
                              void* d_out, int out_size, void* d_ws,
                              size_t ws_size, hipStream_t stream) {
  const float* x = (const float*)d_in[0];
  const float* Wt = (const float*)d_in[1];
  const float* a1 = (const float*)d_in[2];
  const float* b1 = (const float*)d_in[3];
  const float* a2 = (const float*)d_in[4];
  const float* b2 = (const float*)d_in[5];
  float* out = (float*)d_out;

  // u64 arrays first (8-byte alignment off the ws base).
  u64* key64 = (u64*)d_ws;
  u64* thrkey = key64 + N;
  float* ws = (float*)(thrkey + N);
  float* h = ws;        ws += N * D;
  float* f1 = ws;       ws += N;
  float* f2v = ws;      ws += N;
  int* perm = (int*)ws; ws += N;
  int* ksplit = (int*)ws; ws += N;
  float* wsm = ws;      ws += N;
  float* wbg = ws;      ws += N;
  float* part_s = ws;   ws += CHUNKS * D;
  float* part_b = ws;   ws += CHUNKS * D;
  float* off_s = ws;    ws += CHUNKS * D;
  float* off_b = ws;    ws += CHUNKS * D;
  float* pp = ws;       ws += (N + 1);
  float* ss = ws;       ws += (N + 1);
  float* Pm = ws;       ws += (size_t)(N + 1) * D;
  float* Sm = ws;       ws += (size_t)(N + 1) * D;

  k1_gemm<<<N / 16, 256, 0, stream>>>(x, Wt, a1, b1, a2, b2, h, f1, f2v,
                                      key64, thrkey);
  k2_count<<<(2 * N) / 64, 256, 0, stream>>>(key64, thrkey, f2v, perm, wsm,
                                             wbg, ksplit);
  k3a_partials<<<CHUNKS, 256, 0, stream>>>(h, perm, wsm, wbg, part_s, part_b);
  k3b_offsets<<<1, 256, 0, stream>>>(part_s, part_b, off_s, off_b, wsm, wbg,
                                     pp, ss);
  k3c_scan<<<CHUNKS, 64, 0, stream>>>(h, perm, wsm, wbg, off_s, off_b, Pm, Sm);
  k4_out<<<(N * D) / 256, 256, 0, stream>>>(f1, ksplit, pp, ss, Pm, Sm, out);
}

// Round 3
// 115.993 us; speedup vs baseline: 1.7572x; 1.3202x over previous
//
#include <hip/hip_runtime.h>
#include <math.h>

#define N 8192
#define D 64
#define CHUNKS 512
#define CROWS 16   // N / CHUNKS
#define KS 32      // key slices for counting
#define SLICE 256  // N / KS
#define NQ (2 * N) // 16384 queries: 8192 element ranks + 8192 row thresholds

typedef unsigned long long u64;

__device__ __forceinline__ unsigned ordered_bits(float v) {
  unsigned u = __float_as_uint(v);
  return u ^ (((int)u >> 31) | 0x80000000u);
}

// K1: h = x @ Wt; f1 = h@a1+b1; f2 = h@a2+b2; emit strictly-distinct 64-bit
// sort keys for f2 and per-row threshold keys for -f1.
__global__ __launch_bounds__(256) void k1_gemm(
    const float* __restrict__ x, const float* __restrict__ Wt,
    const float* __restrict__ a1, const float* __restrict__ b1,
    const float* __restrict__ a2, const float* __restrict__ b2,
    float* __restrict__ h, float* __restrict__ f1, float* __restrict__ f2,
    u64* __restrict__ key64, u64* __restrict__ thrkey) {
  __shared__ float WtS[D * D];
  __shared__ float xs[16 * D];
  int t = threadIdx.x;
  int rowBase = blockIdx.x * 16;
  for (int i = t; i < D * D; i += 256) WtS[i] = Wt[i];
  for (int i = t; i < 16 * D; i += 256) xs[i] = x[rowBase * D + i];
  __syncthreads();
  int d = t & 63;
  int w = t >> 6;
  float a1d = a1[d], a2d = a2[d];
  float b1v = b1[0], b2v = b2[0];
  for (int it = 0; it < 4; ++it) {
    int rl = w + it * 4;
    float acc = 0.f;
#pragma unroll
    for (int k = 0; k < D; ++k) acc += xs[rl * D + k] * WtS[k * D + d];
    int grow = rowBase + rl;
    h[grow * D + d] = acc;
    float v1 = acc * a1d;
    float v2 = acc * a2d;
#pragma unroll
    for (int off = 32; off > 0; off >>= 1) {
      v1 += __shfl_xor(v1, off);
      v2 += __shfl_xor(v2, off);
    }
    if (d == 0) {
      float F1 = v1 + b1v;
      float F2 = v2 + b2v;
      f1[grow] = F1;
      f2[grow] = F2;
      key64[grow] = ((u64)ordered_bits(F2) << 13) | (unsigned)grow;
      thrkey[grow] = ((u64)ordered_bits(-F1) << 13);
    }
  }
}

// K2a: partial counting rank. Block (g,s): query group g (1024 queries,
// 4/thread) vs key slice s (256 keys staged in LDS). part[s][q] = partial cnt.
__global__ __launch_bounds__(256) void k2a_count(
    const u64* __restrict__ key64, const u64* __restrict__ thrkey,
    int* __restrict__ part) {
  __shared__ u64 ksl[SLICE];
  int t = threadIdx.x;
  int g = blockIdx.x >> 5;        // 0..15
  int s = blockIdx.x & (KS - 1);  // 0..31
  ksl[t] = key64[s * SLICE + t];
  int q0 = g * 1024 + t;
  u64 qa = (q0 < N) ? key64[q0] : thrkey[q0 - N];
  int q1 = q0 + 256;
  u64 qb = (q1 < N) ? key64[q1] : thrkey[q1 - N];
  int q2 = q0 + 512;
  u64 qc = (q2 < N) ? key64[q2] : thrkey[q2 - N];
  int q3 = q0 + 768;
  u64 qd = (q3 < N) ? key64[q3] : thrkey[q3 - N];
  __syncthreads();
  int c0 = 0, c1 = 0, c2 = 0, c3 = 0;
#pragma unroll 8
  for (int l = 0; l < SLICE; ++l) {
    u64 k = ksl[l];
    c0 += (k < qa) ? 1 : 0;
    c1 += (k < qb) ? 1 : 0;
    c2 += (k < qc) ? 1 : 0;
    c3 += (k < qd) ? 1 : 0;
  }
  int* pb = part + s * NQ;
  pb[q0] = c0;
  pb[q1] = c1;
  pb[q2] = c2;
  pb[q3] = c3;
}

// K2b: reduce the KS partials per query; scatter perm/weights (element
// queries) or write per-row split point (threshold queries).
__global__ __launch_bounds__(256) void k2b_reduce(
    const int* __restrict__ part, const float* __restrict__ f2,
    int* __restrict__ perm, float* __restrict__ wsm, float* __restrict__ wbg,
    int* __restrict__ ksplit) {
  int q = blockIdx.x * 256 + threadIdx.x;
  int tot = 0;
#pragma unroll
  for (int s = 0; s < KS; ++s) tot += part[s * NQ + q];
  if (q < N) {
    float v = f2[q];
    perm[tot] = q;
    wsm[tot] = expf(0.2f * v);
    wbg[tot] = expf(v);
  } else {
    ksplit[q - N] = tot;
  }
}

// K3c: per-chunk LOCAL scans (exclusive prefix with small weights, inclusive
// suffix with big weights) for the 64-dim vectors and the scalar weights,
// plus per-chunk totals for the global offset pass.
__global__ __launch_bounds__(64) void k3c_scan(
    const float* __restrict__ h, const int* __restrict__ perm,
    const float* __restrict__ wsm, const float* __restrict__ wbg,
    float* __restrict__ Pl, float* __restrict__ Sl,
    float* __restrict__ tot_s, float* __restrict__ tot_b,
    float* __restrict__ pl, float* __restrict__ sl,
    float* __restrict__ tots_sc, float* __restrict__ totb_sc) {
  __shared__ float hs[CROWS * D];
  int c = blockIdx.x;
  int d = threadIdx.x;
  int base = c * CROWS;
  int pj = (d < CROWS) ? perm[base + d] : 0;
  float wSv = (d < CROWS) ? wsm[base + d] : 0.f;
  float wBv = (d < CROWS) ? wbg[base + d] : 0.f;
#pragma unroll
  for (int r = 0; r < CROWS; ++r) {
    int j = __shfl(pj, r);
    hs[r * D + d] = h[(size_t)j * D + d];
  }
  // scalar lane-scans over lanes 0..CROWS-1
  float incS = wSv, incB = wBv;
#pragma unroll
  for (int off = 1; off < CROWS; off <<= 1) {
    float uS = __shfl_up(incS, off);
    float uB = __shfl_up(incB, off);
    if ((d & 63) >= off) {
      incS += uS;
      incB += uB;
    }
  }
  float totS = __shfl(incS, CROWS - 1);
  float totB = __shfl(incB, CROWS - 1);
  if (d < CROWS) {
    pl[base + d] = incS - wSv;           // exclusive prefix, small weights
    sl[base + d] = totB - (incB - wBv);  // inclusive suffix, big weights
  }
  if (d == 0) {
    tots_sc[c] = totS;
    totb_sc[c] = totB;
  }
  __syncthreads();
  // vector scans (exact serial within chunk)
  float runP = 0.f;
#pragma unroll
  for (int r = 0; r < CROWS; ++r) {
    Pl[(size_t)(base + r) * D + d] = runP;
    runP += __shfl(wSv, r) * hs[r * D + d];
  }
  tot_s[c * D + d] = runP;
  float runS = 0.f;
#pragma unroll
  for (int r = CROWS - 1; r >= 0; --r) {
    runS += __shfl(wBv, r) * hs[r * D + d];
    Sl[(size_t)(base + r) * D + d] = runS;
  }
  tot_b[c * D + d] = runS;
}

// K3b: scan chunk totals into global offsets (prefix for small-weight side,
// exclusive suffix for big-weight side), vector and scalar; zero sentinels.
__global__ __launch_bounds__(256) void k3b_offsets(
    const float* __restrict__ tot_s, const float* __restrict__ tot_b,
    const float* __restrict__ tots_sc, const float* __restrict__ totb_sc,
    float* __restrict__ off_s, float* __restrict__ off_b,
    float* __restrict__ poff, float* __restrict__ soff,
    float* __restrict__ Pl, float* __restrict__ Sl,
    float* __restrict__ pl, float* __restrict__ sl) {
  int t = threadIdx.x;
  if (t < 64) {
    int d = t;
    float run = 0.f;
    for (int c = 0; c < CHUNKS; ++c) {
      off_s[c * D + d] = run;
      run += tot_s[c * D + d];
    }
    off_s[CHUNKS * D + d] = run;
    Pl[(size_t)N * D + d] = 0.f;
    Sl[(size_t)N * D + d] = 0.f;
  } else if (t < 128) {
    int d = t - 64;
    float run = 0.f;
    for (int c = CHUNKS - 1; c >= 0; --c) {
      off_b[c * D + d] = run;
      run += tot_b[c * D + d];
    }
    off_b[CHUNKS * D + d] = 0.f * run + 0.f;  // keep run live; write 0? no:
  } else if (t == 128) {
    float run = 0.f;
    for (int c = 0; c < CHUNKS; ++c) {
      poff[c] = run;
      run += tots_sc[c];
    }
    poff[CHUNKS] = run;
    pl[N] = 0.f;
  } else if (t == 129) {
    float run = 0.f;
    soff[CHUNKS] = 0.f;
    for (int c = CHUNKS - 1; c >= 0; --c) {
      soff[c] = run;
      run += totb_sc[c];
    }
    sl[N] = 0.f;
  }
  // fix: off_b sentinel (exclusive suffix at virtual chunk CHUNKS is 0)
  if (t >= 64 && t < 128) {
    int d = t - 64;
    off_b[CHUNKS * D + d] = 0.f;
  }
}

// K4: per (row, dim): k = precomputed split; combine global offset + local
// scan values; normalize; ELU.
__global__ __launch_bounds__(256) void k4_out(
    const float* __restrict__ f1, const int* __restrict__ ksplit,
    const float* __restrict__ off_s, const float* __restrict__ off_b,
    const float* __restrict__ poff, const float* __restrict__ soff,
    const float* __restrict__ Pl, const float* __restrict__ Sl,
    const float* __restrict__ pl, const float* __restrict__ sl,
    float* __restrict__ out) {
  int g = blockIdx.x * 256 + threadIdx.x;
  int row = g >> 6, d = g & 63;
  float f1v = f1[row];
  int k = ksplit[row];
  int c = k >> 4;  // CROWS == 16; k == N -> c == CHUNKS (sentinel)
  float e1 = expf(f1v), e2 = expf(0.2f * f1v);
  float Sv = off_b[c * D + d] + Sl[(size_t)k * D + d];
  float Pv = off_s[c * D + d] + Pl[(size_t)k * D + d];
  float num = e1 * Sv + e2 * Pv;
  float den = e1 * (soff[c] + sl[k]) + e2 * (poff[c] + pl[k]);
  float v = num / den;
  out[g] = v > 0.f ? v : expm1f(v);
}

extern "C" void kernel_launch(void* const* d_in, const int* in_sizes, int n_in,
                              void* d_out, int out_size, void* d_ws,
                              size_t ws_size, hipStream_t stream) {
  const float* x = (const float*)d_in[0];
  const float* Wt = (const float*)d_in[1];
  const float* a1 = (const float*)d_in[2];
  const float* b1 = (const float*)d_in[3];
  const float* a2 = (const float*)d_in[4];
  const float* b2 = (const float*)d_in[5];
  float* out = (float*)d_out;

  u64* key64 = (u64*)d_ws;
  u64* thrkey = key64 + N;
  float* ws = (float*)(thrkey + N);
  float* h = ws;          ws += N * D;
  float* f1 = ws;         ws += N;
  float* f2v = ws;        ws += N;
  float* wsm = ws;        ws += N;
  float* wbg = ws;        ws += N;
  int* perm = (int*)ws;   ws += N;
  int* ksplit = (int*)ws; ws += N;
  int* part = (int*)ws;   ws += KS * NQ;
  float* Pl = ws;         ws += (size_t)(N + 1) * D;
  float* Sl = ws;         ws += (size_t)(N + 1) * D;
  float* tot_s = ws;      ws += CHUNKS * D;
  float* tot_b = ws;      ws += CHUNKS * D;
  float* off_s = ws;      ws += (CHUNKS + 1) * D;
  float* off_b = ws;      ws += (CHUNKS + 1) * D;
  float* pl = ws;         ws += (N + 1);
  float* sl = ws;         ws += (N + 1);
  float* tots_sc = ws;    ws += CHUNKS;
  float* totb_sc = ws;    ws += CHUNKS;
  float* poff = ws;       ws += (CHUNKS + 1);
  float* soff = ws;       ws += (CHUNKS + 1);

  k1_gemm<<<N / 16, 256, 0, stream>>>(x, Wt, a1, b1, a2, b2, h, f1, f2v,
                                      key64, thrkey);
  k2a_count<<<16 * KS, 256, 0, stream>>>(key64, thrkey, part);
  k2b_reduce<<<NQ / 256, 256, 0, stream>>>(part, f2v, perm, wsm, wbg, ksplit);
  k3c_scan<<<CHUNKS, 64, 0, stream>>>(h, perm, wsm, wbg, Pl, Sl, tot_s, tot_b,
                                      pl, sl, tots_sc, totb_sc);
  k3b_offsets<<<1, 256, 0, stream>>>(tot_s, tot_b, tots_sc, totb_sc, off_s,
                                     off_b, poff, soff, Pl, Sl, pl, sl);
  k4_out<<<(N * D) / 256, 256, 0, stream>>>(f1, ksplit, off_s, off_b, poff,
                                            soff, Pl, Sl, pl, sl, out);
}